// Round 4
// baseline (622.994 us; speedup 1.0000x reference)
//
#include <hip/hip_runtime.h>
#include <hip/hip_bf16.h>
#include <math.h>

#define DEVI __device__ __forceinline__

typedef __bf16 bf16x8 __attribute__((ext_vector_type(8)));
typedef float f32x4 __attribute__((ext_vector_type(4)));
typedef unsigned int u32x4 __attribute__((ext_vector_type(4)));
typedef unsigned short u16;

// s_waitcnt immediates (gfx9 encoding: vm[3:0]|exp[6:4]|lgkm[11:8]|vm_hi[15:14])
#define WAIT_VM0   __builtin_amdgcn_s_waitcnt(0x0F70)  // vmcnt(0), ignore exp/lgkm
#define WAIT_LGKM0 __builtin_amdgcn_s_waitcnt(0xC07F)  // lgkmcnt(0), ignore vm/exp

DEVI u16 f2bf(float f) {
    __hip_bfloat16 h = __float2bfloat16(f);
    return __builtin_bit_cast(u16, h);
}
DEVI float bf2f(u16 u) {
    unsigned int x = ((unsigned int)u) << 16;
    return __builtin_bit_cast(float, x);
}
DEVI float gelu_f(float x) { return 0.5f * x * (1.f + erff(x * 0.70710678118654752f)); }
DEVI float sigm(float x) { return 1.f / (1.f + __expf(-x)); }

DEVI bf16x8 ldfrag(const u16* p) {
    return __builtin_bit_cast(bf16x8, *reinterpret_cast<const u32x4*>(p));
}

// async global->LDS, 16B/lane; LDS dest = wave-uniform base + lane*16
DEVI void gload_lds16(const u16* g, u16* l) {
    __builtin_amdgcn_global_load_lds(
        (const __attribute__((address_space(1))) void*)g,
        (__attribute__((address_space(3))) void*)l, 16, 0, 0);
}

// Swizzled tile staging: rows x 64 u16 per row; stored chunk position p of row r
// holds global k-chunk p ^ (r&7)  ->  fragment reads are 2-way-conflict max.
// One call stages 8 rows (1KB). lane -> (row=lane>>3, pos=lane&7).
DEVI void stage8(const u16* gbase, long long stride, u16* lds, int lane) {
    int r = lane >> 3;
    int kg = (lane & 7) ^ r;
    gload_lds16(gbase + (long long)r * stride + kg * 8, lds);
}
// fragment read: row rr, logical k-chunk k (0..7) of a 64-wide swizzled tile
DEVI bf16x8 fragsw(const u16* tile, int rr, int k) {
    return ldfrag(&tile[rr * 64 + ((k ^ (rr & 7)) << 3)]);
}

// ---------------- zero fill ----------------
__global__ __launch_bounds__(256) void zero_k(float* __restrict__ p) {
    p[(long long)blockIdx.x * 256 + threadIdx.x] = 0.f;
}

// ---------------- transpose + cast fp32 -> bf16 ----------------
__global__ __launch_bounds__(256) void tcast_k(const float* __restrict__ in, u16* __restrict__ out,
                                               int R, int C) {
    __shared__ float tile[32][33];
    int c0 = blockIdx.x * 32, r0 = blockIdx.y * 32;
    for (int ry = threadIdx.y; ry < 32; ry += 8)
        tile[ry][threadIdx.x] = in[(long long)(r0 + ry) * C + c0 + threadIdx.x];
    __syncthreads();
    for (int cy = threadIdx.y; cy < 32; cy += 8)
        out[(long long)(c0 + cy) * R + r0 + threadIdx.x] = f2bf(tile[threadIdx.x][cy]);
}

// ---------------- layernorm over 768 ----------------
__global__ __launch_bounds__(256) void ln_k(const float* __restrict__ in1, const float* __restrict__ in2,
                                            const float* __restrict__ w, const float* __restrict__ b,
                                            u16* __restrict__ outbf, float* __restrict__ x1out) {
    int row = blockIdx.x;
    long long ro = (long long)row * 768;
    __shared__ float lds1[4], lds2[4];
    float v[3];
    float s = 0.f, sq = 0.f;
#pragma unroll
    for (int j = 0; j < 3; j++) {
        int c = threadIdx.x + j * 256;
        float x = in1[ro + c];
        if (in2) x += in2[ro + c];
        v[j] = x; s += x; sq += x * x;
    }
    if (x1out) {
#pragma unroll
        for (int j = 0; j < 3; j++) x1out[ro + threadIdx.x + j * 256] = v[j];
    }
    for (int off = 32; off; off >>= 1) { s += __shfl_down(s, off); sq += __shfl_down(sq, off); }
    int wid = threadIdx.x >> 6;
    if ((threadIdx.x & 63) == 0) { lds1[wid] = s; lds2[wid] = sq; }
    __syncthreads();
    s = lds1[0] + lds1[1] + lds1[2] + lds1[3];
    sq = lds2[0] + lds2[1] + lds2[2] + lds2[3];
    float mu = s * (1.f / 768.f);
    float var = sq * (1.f / 768.f) - mu * mu;
    float rs = rsqrtf(var + 1e-5f);
#pragma unroll
    for (int j = 0; j < 3; j++) {
        int c = threadIdx.x + j * 256;
        outbf[ro + c] = f2bf((v[j] - mu) * rs * w[c] + b[c]);
    }
}

// ---------------- single-wave MFMA GEMM: C = A @ B_t^T, 64x64 tile, BK=64 ----------------
struct GemmP {
    const u16* A; const u16* B;
    float* outF; u16* outB;
    const float* bias; const float* res;
    int M, N, K, lda, ldb, ldc;
    int epi;     // 0:f32+bias 1:bf16+bias 2:bf16+bias+gelu 3:f32+bias+res
    int splits;  // if >1: atomicAdd fp32 out (pre-zeroed); split 0 adds bias(+res)
};

__global__ __launch_bounds__(64) void gemm1w(GemmP p) {
    __shared__ u16 As[64 * 64];
    __shared__ u16 Bs[64 * 64];
    const int lane = threadIdx.x;
    const int l16 = lane & 15, qd = lane >> 4;
    const int bn0 = blockIdx.x * 64, bm0 = blockIdx.y * 64;
    const int kc = p.K / p.splits;
    const int kbeg = blockIdx.z * kc, kend = kbeg + kc;
    f32x4 acc[4][4] = {};
    for (int k0 = kbeg; k0 < kend; k0 += 64) {
        WAIT_LGKM0;  // prior iter's ds_reads retired before LDS overwrite
        const u16* Ab = p.A + (long long)bm0 * p.lda + k0;
        const u16* Bb = p.B + (long long)bn0 * p.ldb + k0;
#pragma unroll
        for (int t = 0; t < 8; t++) stage8(Ab + (long long)t * 8 * p.lda, p.lda, As + t * 512, lane);
#pragma unroll
        for (int t = 0; t < 8; t++) stage8(Bb + (long long)t * 8 * p.ldb, p.ldb, Bs + t * 512, lane);
        WAIT_VM0;
#pragma unroll
        for (int s = 0; s < 2; s++) {
            bf16x8 af[4], bv[4];
#pragma unroll
            for (int i = 0; i < 4; i++) af[i] = fragsw(As, i * 16 + l16, s * 4 + qd);
#pragma unroll
            for (int j = 0; j < 4; j++) bv[j] = fragsw(Bs, j * 16 + l16, s * 4 + qd);
#pragma unroll
            for (int i = 0; i < 4; i++)
#pragma unroll
                for (int j = 0; j < 4; j++)
                    acc[i][j] = __builtin_amdgcn_mfma_f32_16x16x32_bf16(af[i], bv[j], acc[i][j], 0, 0, 0);
        }
    }
#pragma unroll
    for (int i = 0; i < 4; i++)
#pragma unroll
        for (int j = 0; j < 4; j++)
#pragma unroll
            for (int r = 0; r < 4; r++) {
                int row = bm0 + i * 16 + qd * 4 + r;
                int col = bn0 + j * 16 + l16;
                float v = acc[i][j][r];
                long long o = (long long)row * p.ldc + col;
                if (p.splits == 1) {
                    switch (p.epi) {
                        case 0: p.outF[o] = v + p.bias[col]; break;
                        case 1: p.outB[o] = f2bf(v + p.bias[col]); break;
                        case 2: p.outB[o] = f2bf(gelu_f(v + p.bias[col])); break;
                        default: p.outF[o] = v + p.bias[col] + p.res[o]; break;
                    }
                } else {
                    if (blockIdx.z == 0) {
                        v += p.bias[col];
                        if (p.epi == 3) v += p.res[o];
                    }
                    atomicAdd(&p.outF[o], v);
                }
            }
}

// ---------------- repack qkv (bf16 [4096][2304]) into per-head q,k,v [48][1024][64] ----------------
__global__ __launch_bounds__(256) void repack_qkv_k(const u16* __restrict__ qkvB,
                                                    u16* __restrict__ qh, u16* __restrict__ kh,
                                                    u16* __restrict__ vh) {
    long long idx = (long long)blockIdx.x * 256 + threadIdx.x;
    int r = (int)(idx / 768), c = (int)(idx % 768);
    int b = r >> 10, n = r & 1023, h = c >> 6, d = c & 63;
    long long src = (long long)r * 2304;
    long long o = ((long long)(b * 12 + h) * 1024 + n) * 64 + d;
    qh[o] = f2bf(bf2f(qkvB[src + c]) * 0.125f);
    kh[o] = qkvB[src + 768 + c];
    vh[o] = qkvB[src + 1536 + c];
}

// ---------------- gwn = softmax(gelu(v @ gp^T)) per head, padded to 64 cols, bf16 ----------------
__global__ __launch_bounds__(256) void gw0_k(const u16* __restrict__ vh, const float* __restrict__ gp_w,
                                             u16* __restrict__ gwn) {
    int z = blockIdx.y, n0 = blockIdx.x * 64;
    int h = z % 12;
    __shared__ float gps[49 * 64];
    __shared__ float vs[64 * 64];
    __shared__ float gws[64 * 52];
    for (int i = threadIdx.x; i < 49 * 64; i += 256) gps[i] = gp_w[h * 3136 + i];
    for (int i = threadIdx.x; i < 64 * 64; i += 256) {
        int n = i >> 6, d = i & 63;
        vs[i] = bf2f(vh[((long long)z * 1024 + n0 + n) * 64 + d]);
    }
    __syncthreads();
    for (int o = threadIdx.x; o < 64 * 49; o += 256) {
        int n = o / 49, m = o % 49;
        float s = 0.f;
#pragma unroll 8
        for (int kk = 0; kk < 64; kk++) s += vs[n * 64 + kk] * gps[m * 64 + kk];
        gws[n * 52 + m] = gelu_f(s);
    }
    __syncthreads();
    if (threadIdx.x < 64) {
        int n = threadIdx.x;
        float mx = -1e30f;
        for (int m = 0; m < 49; m++) mx = fmaxf(mx, gws[n * 52 + m]);
        float se = 0.f;
        for (int m = 0; m < 49; m++) se += __expf(gws[n * 52 + m] - mx);
        float inv = 1.f / se;
        long long o = ((long long)z * 1024 + n0 + n) * 64;
        for (int m = 0; m < 49; m++) gwn[o + m] = f2bf(__expf(gws[n * 52 + m] - mx) * inv);
        for (int m = 49; m < 64; m++) gwn[o + m] = 0;
    }
}

// ---------------- single-wave: e = exp((q@k^T)*(gwn@gwn^T)) bf16, + fp32 rowsums ----------------
__global__ __launch_bounds__(64) void attn_tg_1w(const u16* __restrict__ qh, const u16* __restrict__ kh,
                                                 const u16* __restrict__ gwn, u16* __restrict__ e,
                                                 float* __restrict__ rowsumE) {
    __shared__ u16 As[64 * 64];
    __shared__ u16 Bs[64 * 64];
    const int lane = threadIdx.x;
    const int l16 = lane & 15, qd = lane >> 4;
    const int bn0 = blockIdx.x * 64, bm0 = blockIdx.y * 64, z = blockIdx.z;
    const u16* qz = qh + (long long)z * 65536;
    const u16* kz = kh + (long long)z * 65536;
    const u16* gz = gwn + (long long)z * 65536;
    f32x4 accS[4][4] = {};
    f32x4 accG[4][4] = {};
    // phase 1: q @ k^T
#pragma unroll
    for (int t = 0; t < 8; t++) stage8(qz + (long long)(bm0 + t * 8) * 64, 64, As + t * 512, lane);
#pragma unroll
    for (int t = 0; t < 8; t++) stage8(kz + (long long)(bn0 + t * 8) * 64, 64, Bs + t * 512, lane);
    WAIT_VM0;
#pragma unroll
    for (int s = 0; s < 2; s++) {
        bf16x8 af[4], bv[4];
#pragma unroll
        for (int i = 0; i < 4; i++) af[i] = fragsw(As, i * 16 + l16, s * 4 + qd);
#pragma unroll
        for (int j = 0; j < 4; j++) bv[j] = fragsw(Bs, j * 16 + l16, s * 4 + qd);
#pragma unroll
        for (int i = 0; i < 4; i++)
#pragma unroll
            for (int j = 0; j < 4; j++)
                accS[i][j] = __builtin_amdgcn_mfma_f32_16x16x32_bf16(af[i], bv[j], accS[i][j], 0, 0, 0);
    }
    WAIT_LGKM0;
    // phase 2: gwn @ gwn^T
#pragma unroll
    for (int t = 0; t < 8; t++) stage8(gz + (long long)(bm0 + t * 8) * 64, 64, As + t * 512, lane);
#pragma unroll
    for (int t = 0; t < 8; t++) stage8(gz + (long long)(bn0 + t * 8) * 64, 64, Bs + t * 512, lane);
    WAIT_VM0;
#pragma unroll
    for (int s = 0; s < 2; s++) {
        bf16x8 af[4], bv[4];
#pragma unroll
        for (int i = 0; i < 4; i++) af[i] = fragsw(As, i * 16 + l16, s * 4 + qd);
#pragma unroll
        for (int j = 0; j < 4; j++) bv[j] = fragsw(Bs, j * 16 + l16, s * 4 + qd);
#pragma unroll
        for (int i = 0; i < 4; i++)
#pragma unroll
            for (int j = 0; j < 4; j++)
                accG[i][j] = __builtin_amdgcn_mfma_f32_16x16x32_bf16(af[i], bv[j], accG[i][j], 0, 0, 0);
    }
    long long zoff = (long long)z * 1048576;
#pragma unroll
    for (int i = 0; i < 4; i++)
#pragma unroll
        for (int r = 0; r < 4; r++) {
            int row = bm0 + i * 16 + qd * 4 + r;
            float rs = 0.f;
#pragma unroll
            for (int j = 0; j < 4; j++) {
                int col = bn0 + j * 16 + l16;
                float ev = __expf(accS[i][j][r] * accG[i][j][r]);  // |t| small, no max-sub
                e[zoff + (long long)row * 1024 + col] = f2bf(ev);
                rs += ev;
            }
            rs += __shfl_xor(rs, 1); rs += __shfl_xor(rs, 2);
            rs += __shfl_xor(rs, 4); rs += __shfl_xor(rs, 8);
            if (l16 == 0) atomicAdd(&rowsumE[z * 1024 + row], rs);
        }
}

// ---------------- S[z][j] = sum_n gwn[z][n][j] ----------------
__global__ __launch_bounds__(256) void sgw_k(const u16* __restrict__ gwn, float* __restrict__ S) {
    int z = blockIdx.x;
    int j = threadIdx.x & 63, part = threadIdx.x >> 6;
    __shared__ float lds[4][64];
    float s = 0.f;
    for (int i = 0; i < 256; i++)
        s += bf2f(gwn[((long long)z * 1024 + part * 256 + i) * 64 + j]);
    lds[part][j] = s;
    __syncthreads();
    if (threadIdx.x < 64) S[z * 64 + threadIdx.x] =
        lds[0][threadIdx.x] + lds[1][threadIdx.x] + lds[2][threadIdx.x] + lds[3][threadIdx.x];
}

// ---------------- colsum init: colsum[z][m] = a * (gwn[m] . S) ----------------
__global__ __launch_bounds__(256) void combine_k(const u16* __restrict__ gwn, const float* __restrict__ S,
                                                 const float* __restrict__ alpha, float* __restrict__ colsum) {
    int m = blockIdx.x * 256 + threadIdx.x;
    int z = blockIdx.y, h = z % 12;
    float a = sigm(alpha[h]);
    const u16* g = gwn + ((long long)z * 1024 + m) * 64;
    const float* Sz = S + z * 64;
    float dot = 0.f;
#pragma unroll 8
    for (int j = 0; j < 64; j++) dot += bf2f(g[j]) * Sz[j];
    colsum[z * 1024 + m] = a * dot;
}

// ---------------- colsum[z][m] += (1-a) * sum_n e[n][m]/rowsum[n] ----------------
__global__ __launch_bounds__(256) void colsumE_k(const u16* __restrict__ e, const float* __restrict__ rowsumE,
                                                 const float* __restrict__ alpha, float* __restrict__ colsum) {
    int m = blockIdx.x * 256 + threadIdx.x;
    int n0 = blockIdx.y * 128;
    int z = blockIdx.z, h = z % 12;
    float a = sigm(alpha[h]);
    const u16* p = e + (long long)z * 1048576;
    const float* rs = rowsumE + z * 1024;
    float s = 0.f;
    for (int n = n0; n < n0 + 128; n++) s += bf2f(p[(long long)n * 1024 + m]) * (1.f / rs[n]);
    atomicAdd(&colsum[z * 1024 + m], (1.f - a) * s);
}

// ---------------- v'^T: vpt[z][d][m] = vh[z][m][d] / (colsum+1e-8), bf16 ----------------
__global__ __launch_bounds__(256) void vpt_k(const u16* __restrict__ vh, const float* __restrict__ colsum,
                                             u16* __restrict__ vpt) {
    int z = blockIdx.y, m0 = blockIdx.x * 64;
    __shared__ float ts[64 * 65];
    int mi = threadIdx.x >> 6, d = threadIdx.x & 63;
    for (int rr = 0; rr < 16; rr++) {
        int row = rr * 4 + mi;
        ts[row * 65 + d] = bf2f(vh[((long long)z * 1024 + m0 + row) * 64 + d]);
    }
    __syncthreads();
    int mj = threadIdx.x & 63, d0 = threadIdx.x >> 6;
    for (int rr = 0; rr < 16; rr++) {
        int dd = rr * 4 + d0;
        float cs = colsum[z * 1024 + m0 + mj] + 1e-8f;
        vpt[((long long)z * 64 + dd) * 1024 + m0 + mj] = f2bf(ts[mj * 65 + dd] / cs);
    }
}

// ---------------- Wt[z][d][j] = sum_n gwn[z][n][j] * v'[z][n][d] ----------------
__global__ __launch_bounds__(256) void wgemm_k(const u16* __restrict__ gwn, const u16* __restrict__ vpt,
                                               float* __restrict__ Wt) {
    int z = blockIdx.y, n0 = blockIdx.x * 128;
    __shared__ u16 gs[128 * 64];
    __shared__ u16 vs2[64 * 128];
    for (int i = threadIdx.x; i < 128 * 64; i += 256) {
        int nn = i >> 6, j = i & 63;
        gs[i] = gwn[((long long)z * 1024 + n0 + nn) * 64 + j];
        int d = i >> 7, n2 = i & 127;
        vs2[i] = vpt[((long long)z * 64 + d) * 1024 + n0 + n2];
    }
    __syncthreads();
    int j = threadIdx.x & 63, dg = threadIdx.x >> 6;
    float acc[16] = {};
    for (int nn = 0; nn < 128; nn++) {
        float g = bf2f(gs[nn * 64 + j]);
#pragma unroll
        for (int i = 0; i < 16; i++) acc[i] += g * bf2f(vs2[(dg * 16 + i) * 128 + nn]);
    }
#pragma unroll
    for (int i = 0; i < 16; i++)
        atomicAdd(&Wt[((long long)z * 64 + dg * 16 + i) * 64 + j], acc[i]);
}

// ---------------- Wt fp32 -> bf16 ----------------
__global__ __launch_bounds__(256) void wtcast_k(const float* __restrict__ Wt, u16* __restrict__ WtB) {
    long long i = (long long)blockIdx.x * 256 + threadIdx.x;
    WtB[i] = f2bf(Wt[i]);
}

// ---------------- single-wave: out = (1-a)/rowsum*(e@v') + a*(gwn@W), head-merged bf16 ----------------
__global__ __launch_bounds__(64) void attn_out_1w(const u16* __restrict__ e, const u16* __restrict__ vpt,
                                                  const u16* __restrict__ gwn, const u16* __restrict__ WtB,
                                                  const float* __restrict__ rowsumE,
                                                  const float* __restrict__ alpha, u16* __restrict__ out) {
    __shared__ u16 As[32 * 64];
    __shared__ u16 Bs[64 * 64];
    const int lane = threadIdx.x;
    const int l16 = lane & 15, qd = lane >> 4;
    const int bm0 = blockIdx.x * 32, z = blockIdx.y;
    const int h = z % 12, b = z / 12;
    const u16* Pz = e + (long long)z * 1048576;
    const u16* vz = vpt + (long long)z * 65536;
    f32x4 accP[2][4] = {};
    f32x4 accG[2][4] = {};
    for (int k0 = 0; k0 < 1024; k0 += 64) {
        WAIT_LGKM0;
#pragma unroll
        for (int t = 0; t < 4; t++)
            stage8(Pz + (long long)(bm0 + t * 8) * 1024 + k0, 1024, As + t * 512, lane);
#pragma unroll
        for (int t = 0; t < 8; t++)
            stage8(vz + (long long)(t * 8) * 1024 + k0, 1024, Bs + t * 512, lane);
        WAIT_VM0;
#pragma unroll
        for (int s = 0; s < 2; s++) {
            bf16x8 af[2], bv[4];
#pragma unroll
            for (int i = 0; i < 2; i++) af[i] = fragsw(As, i * 16 + l16, s * 4 + qd);
#pragma unroll
            for (int j = 0; j < 4; j++) bv[j] = fragsw(Bs, j * 16 + l16, s * 4 + qd);
#pragma unroll
            for (int i = 0; i < 2; i++)
#pragma unroll
                for (int j = 0; j < 4; j++)
                    accP[i][j] = __builtin_amdgcn_mfma_f32_16x16x32_bf16(af[i], bv[j], accP[i][j], 0, 0, 0);
        }
    }
    WAIT_LGKM0;
    // G part: gwn(32x64) @ W^T  (WtB rows are d, k over j)
    const u16* gz = gwn + (long long)z * 65536;
    const u16* wz = WtB + (long long)z * 4096;
#pragma unroll
    for (int t = 0; t < 4; t++) stage8(gz + (long long)(bm0 + t * 8) * 64, 64, As + t * 512, lane);
#pragma unroll
    for (int t = 0; t < 8; t++) stage8(wz + (long long)(t * 8) * 64, 64, Bs + t * 512, lane);
    WAIT_VM0;
#pragma unroll
    for (int s = 0; s < 2; s++) {
        bf16x8 af[2], bv[4];
#pragma unroll
        for (int i = 0; i < 2; i++) af[i] = fragsw(As, i * 16 + l16, s * 4 + qd);
#pragma unroll
        for (int j = 0; j < 4; j++) bv[j] = fragsw(Bs, j * 16 + l16, s * 4 + qd);
#pragma unroll
        for (int i = 0; i < 2; i++)
#pragma unroll
            for (int j = 0; j < 4; j++)
                accG[i][j] = __builtin_amdgcn_mfma_f32_16x16x32_bf16(af[i], bv[j], accG[i][j], 0, 0, 0);
    }
    float a = sigm(alpha[h]);
#pragma unroll
    for (int i = 0; i < 2; i++)
#pragma unroll
        for (int r = 0; r < 4; r++) {
            int n = bm0 + i * 16 + qd * 4 + r;
            float sc = (1.f - a) / rowsumE[z * 1024 + n];
#pragma unroll
            for (int j = 0; j < 4; j++) {
                int d = j * 16 + l16;
                float v = sc * accP[i][j][r] + a * accG[i][j][r];
                out[((long long)(b * 1024 + n)) * 768 + h * 64 + d] = f2bf(v);
            }
        }
}

// =======================================================================================
extern "C" void kernel_launch(void* const* d_in, const int* in_sizes, int n_in,
                              void* d_out, int out_size, void* d_ws, size_t ws_size,
                              hipStream_t stream) {
    const float* x      = (const float*)d_in[0];
    const float* ln1_w  = (const float*)d_in[1];
    const float* ln1_b  = (const float*)d_in[2];
    const float* qkv_w  = (const float*)d_in[3];
    const float* qkv_b  = (const float*)d_in[4];
    const float* proj_w = (const float*)d_in[5];
    const float* proj_b = (const float*)d_in[6];
    const float* gp_w   = (const float*)d_in[7];
    const float* alpha  = (const float*)d_in[8];
    const float* ln2_w  = (const float*)d_in[9];
    const float* ln2_b  = (const float*)d_in[10];
    const float* ff1_w  = (const float*)d_in[11];
    const float* ff1_b  = (const float*)d_in[12];
    const float* ff2_w  = (const float*)d_in[13];
    const float* ff2_b  = (const float*)d_in[14];

    char* w = (char*)d_ws;
    size_t off = 0;
    auto alloc = [&](size_t bytes) { size_t r = off; off += (bytes + 255) & ~(size_t)255; return r; };

    u16*   xn_bf   = (u16*)(w + alloc(4096LL * 768 * 2));
    u16*   wqkv_t  = (u16*)(w + alloc(2304LL * 768 * 2));
    u16*   wproj_t = (u16*)(w + alloc(768LL * 768 * 2));
    u16*   wff1_t  = (u16*)(w + alloc(3072LL * 768 * 2));
    u16*   wff2_t  = (u16*)(w + alloc(768LL * 3072 * 2));
    u16*   qkvB    = (u16*)(w + alloc(4096LL * 2304 * 2));   // later: attn_o + xn2
    u16*   qh      = (u16*)(w + alloc(48LL * 1024 * 64 * 2));
    u16*   kh      = (u16*)(w + alloc(48LL * 1024 * 64 * 2));
    u16*   vh      = (u16*)(w + alloc(48LL * 1024 * 64 * 2));
    u16*   gwn     = (u16*)(w + alloc(48LL * 1024 * 64 * 2));
    u16*   ebuf    = (u16*)(w + alloc(48LL * 1024 * 1024 * 2));  // exp(t); later proj_out + hmid
    float* rowsumE = (float*)(w + alloc(48LL * 1024 * 4));
    float* Sbuf    = (float*)(w + alloc(48LL * 64 * 4));
    float* Wt      = (float*)(w + alloc(48LL * 64 * 64 * 4));
    u16*   WtB     = (u16*)(w + alloc(48LL * 64 * 64 * 2));
    float* colsum  = (float*)(w + alloc(48LL * 1024 * 4));
    u16*   vpt     = (u16*)(w + alloc(48LL * 64 * 1024 * 2));
    float* x1      = (float*)(w + alloc(4096LL * 768 * 4));
    // region reuse (dead buffers)
    u16*   attn_o   = qkvB;                               // qkvB dead after repack/gw0
    u16*   xn2      = qkvB + 4096LL * 768;
    float* proj_out = (float*)ebuf;                       // e dead after attn_out
    u16*   hmid     = (u16*)((char*)ebuf + 4096LL * 768 * 4);

    dim3 blk(256);
    dim3 wv(64);

    // weight transpose-casts
    tcast_k<<<dim3(72, 24), dim3(32, 8), 0, stream>>>(qkv_w, wqkv_t, 768, 2304);
    tcast_k<<<dim3(24, 24), dim3(32, 8), 0, stream>>>(proj_w, wproj_t, 768, 768);
    tcast_k<<<dim3(96, 24), dim3(32, 8), 0, stream>>>(ff1_w, wff1_t, 768, 3072);
    tcast_k<<<dim3(24, 96), dim3(32, 8), 0, stream>>>(ff2_w, wff2_t, 3072, 768);

    // LN1
    ln_k<<<dim3(4096), blk, 0, stream>>>(x, nullptr, ln1_w, ln1_b, xn_bf, nullptr);

    // QKV GEMM -> bf16 qkvB
    {
        GemmP p = {xn_bf, wqkv_t, nullptr, qkvB, qkv_b, nullptr, 4096, 2304, 768, 768, 768, 2304, 1, 1};
        gemm1w<<<dim3(36, 64, 1), wv, 0, stream>>>(p);
    }

    // repack q,k,v ; group weights
    repack_qkv_k<<<dim3(12288), blk, 0, stream>>>(qkvB, qh, kh, vh);
    gw0_k<<<dim3(16, 48), blk, 0, stream>>>(vh, gp_w, gwn);

    // e = exp((q@k^T)*(gwn@gwn^T)) + exact rowsums
    zero_k<<<dim3(192), blk, 0, stream>>>(rowsumE);
    attn_tg_1w<<<dim3(16, 16, 48), wv, 0, stream>>>(qh, kh, gwn, ebuf, rowsumE);

    // colsum = a*(gwn.S) + (1-a)*sum_n e/rowsum
    sgw_k<<<dim3(48), blk, 0, stream>>>(gwn, Sbuf);
    combine_k<<<dim3(4, 48), blk, 0, stream>>>(gwn, Sbuf, alpha, colsum);
    colsumE_k<<<dim3(4, 8, 48), blk, 0, stream>>>(ebuf, rowsumE, alpha, colsum);

    // v'^T
    vpt_k<<<dim3(16, 48), blk, 0, stream>>>(vh, colsum, vpt);

    // Wt = (gwn^T @ v')^T ; cast bf16
    zero_k<<<dim3(768), blk, 0, stream>>>(Wt);
    wgemm_k<<<dim3(8, 48), blk, 0, stream>>>(gwn, vpt, Wt);
    wtcast_k<<<dim3(768), blk, 0, stream>>>(Wt, WtB);

    // attention output (head-merged bf16)
    attn_out_1w<<<dim3(32, 48), wv, 0, stream>>>(ebuf, vpt, gwn, WtB, rowsumE, alpha, attn_o);

    // proj GEMM -> proj_out fp32 (split-K x2, atomic; e dead)
    zero_k<<<dim3(12288), blk, 0, stream>>>(proj_out);
    {
        GemmP p = {attn_o, wproj_t, proj_out, nullptr, proj_b, nullptr, 4096, 768, 768, 768, 768, 768, 0, 2};
        gemm1w<<<dim3(12, 64, 2), wv, 0, stream>>>(p);
    }

    // x1 = proj_out + x ; LN2 -> xn2
    ln_k<<<dim3(4096), blk, 0, stream>>>(proj_out, x, ln2_w, ln2_b, xn2, x1);

    // FF1 + gelu -> hmid bf16
    {
        GemmP p = {xn2, wff1_t, nullptr, hmid, ff1_b, nullptr, 4096, 3072, 768, 768, 768, 3072, 2, 1};
        gemm1w<<<dim3(48, 64, 1), wv, 0, stream>>>(p);
    }

    // FF2 + residual -> d_out fp32 (split-K x4, atomic)
    zero_k<<<dim3(12288), blk, 0, stream>>>((float*)d_out);
    {
        GemmP p = {hmid, wff2_t, (float*)d_out, nullptr, ff2_b, x1, 4096, 768, 3072, 3072, 3072, 768, 3, 4};
        gemm1w<<<dim3(12, 64, 4), wv, 0, stream>>>(p);
    }
}